// Round 2
// baseline (2492.730 us; speedup 1.0000x reference)
//
#include <hip/hip_runtime.h>

typedef unsigned short u16;
typedef unsigned int u32;
typedef unsigned long long u64;

#define NN 8192
#define CAP 128
#define NB 2048   // persistent grid: 8 blocks/CU * 256 CU, guaranteed by __launch_bounds__(256,8)
                  // (VGPR<=64: round-1 compiled this exact phase code to 64 VGPR; LDS 16.4KB<20KB)

typedef __attribute__((ext_vector_type(8))) short short8;
typedef __attribute__((ext_vector_type(4))) float floatx4;

__device__ __forceinline__ u16 f2bf(float f) {
    union { float f; u32 i; } w;
    w.f = f;
    u32 i = w.i;
    return (u16)((i + 0x7FFFu + ((i >> 16) & 1u)) >> 16);
}
__device__ __forceinline__ float lo_bf(u32 v) {
    union { u32 i; float f; } w;
    w.i = v << 16;
    return w.f;
}
__device__ __forceinline__ float hi_bf(u32 v) {
    union { u32 i; float f; } w;
    w.i = v & 0xFFFF0000u;
    return w.f;
}
__device__ __forceinline__ float softplusf(float x) {
    return fmaxf(x, 0.0f) + log1pf(expf(-fabsf(x)));
}

// Quiet monotone grid barrier.
// R1 post-mortem: ACQUIRE polls emit an L1+XCD-L2 invalidate EACH POLL -> 1024
// pollers wiped every XCD L2 every few cycles during every phase tail (the 3.4x
// regression). Fix: one release fence, RELAXED add, RELAXED polls + s_sleep,
// one acquire fence on exit. Cross-XCD visibility still guaranteed:
// __threadfence (wbL2) before add publishes; __threadfence after poll invalidates.
__device__ __forceinline__ void gridbar(u64* bar) {
    __syncthreads();                       // drains this block's vmcnt (stores issued)
    if (threadIdx.x == 0) {
        __threadfence();                   // release: write back dirty L2 once
        u64 a = __hip_atomic_fetch_add(bar, 1ull, __ATOMIC_RELAXED, __HIP_MEMORY_SCOPE_AGENT);
        u64 tgt = (a / NB + 1ull) * (u64)NB;
        while (__hip_atomic_load(bar, __ATOMIC_RELAXED, __HIP_MEMORY_SCOPE_AGENT) < tgt)
            __builtin_amdgcn_s_sleep(16);  // ~1024 cyc poll period, no cache side-effects
        __threadfence();                   // acquire: invalidate stale L1/L2 once
    }
    __syncthreads();
}

// ---------------- SpMM F=128 phase (layer 0) ----------------
__device__ __forceinline__ void spmm128_phase(
    int* sh, const u32* __restrict__ edges, const int* __restrict__ deg,
    const float* __restrict__ snorm,
    const u32* __restrict__ feat1, u32* __restrict__ out1)
{
    const int wave = threadIdx.x >> 6, lane = threadIdx.x & 63;
    for (int vb = blockIdx.x; vb < 2048; vb += NB) {   // exactly 1 iter at NB=2048
        const int j = vb * 4 + wave;
        const int cnt = min(deg[j], CAP);
        __syncthreads();
        int* sh_i = sh + wave * CAP;
        for (int c = lane; c < cnt; c += 64)
            sh_i[c] = (int)edges[(size_t)j * CAP + c];
        __syncthreads();
        float a0 = 0.f, a1 = 0.f;
#pragma unroll 4
        for (int c = 0; c < cnt; ++c) {
            u32 v = feat1[(size_t)sh_i[c] * 64 + lane];
            a0 += lo_bf(v); a1 += hi_bf(v);
        }
        float sj = snorm[j];
        out1[(size_t)j * 64 + lane] = (u32)f2bf(a0 * sj) | ((u32)f2bf(a1 * sj) << 16);
    }
}

// ---------------- SpMM F=512 phase ----------------
__device__ __forceinline__ void spmm512_phase(
    int* sh, const u32* __restrict__ edges, const int* __restrict__ deg,
    const float* __restrict__ snorm,
    const uint4* __restrict__ feat4, uint4* __restrict__ out4)
{
    const int wave = threadIdx.x >> 6, lane = threadIdx.x & 63;
    for (int vb = blockIdx.x; vb < 2048; vb += NB) {   // exactly 1 iter at NB=2048
        const int j = vb * 4 + wave;
        const int cnt = min(deg[j], CAP);
        __syncthreads();
        int* sh_i = sh + wave * CAP;
        for (int c = lane; c < cnt; c += 64)
            sh_i[c] = (int)edges[(size_t)j * CAP + c];
        __syncthreads();
        float a[8] = {};
#pragma unroll 4
        for (int c = 0; c < cnt; ++c) {
            uint4 v = feat4[(size_t)sh_i[c] * 64 + lane];
            a[0] += lo_bf(v.x); a[1] += hi_bf(v.x);
            a[2] += lo_bf(v.y); a[3] += hi_bf(v.y);
            a[4] += lo_bf(v.z); a[5] += hi_bf(v.z);
            a[6] += lo_bf(v.w); a[7] += hi_bf(v.w);
        }
        float sj = snorm[j];
        uint4 o;
        o.x = (u32)f2bf(a[0] * sj) | ((u32)f2bf(a[1] * sj) << 16);
        o.y = (u32)f2bf(a[2] * sj) | ((u32)f2bf(a[3] * sj) << 16);
        o.z = (u32)f2bf(a[4] * sj) | ((u32)f2bf(a[5] * sj) << 16);
        o.w = (u32)f2bf(a[6] * sj) | ((u32)f2bf(a[7] * sj) << 16);
        out4[(size_t)j * 64 + lane] = o;
    }
}

// ---------------- GEMM phase: out = softplus(A[8192,K] @ W + b) ----------------
// 64x64 tile; 1024 tiles; blocks >=1024 skip (caller guards).
// XOR-swizzled LDS (conflict-free) + async global_load_lds — unchanged.
__device__ __forceinline__ void gemm_phase(
    u16* lA, u16* lB,
    const u16* __restrict__ A, const u16* __restrict__ BT,
    const float* __restrict__ bias, const float* __restrict__ snorm,
    float* __restrict__ outf, u16* __restrict__ outb, int K)
{
    const int tid = threadIdx.x;
    const int wave = tid >> 6;
    const int lane = tid & 63;
    const int q = lane >> 4;
    const int m16 = lane & 15;
    const int wm = (wave >> 1) * 32;
    const int wn = (wave & 1) * 32;
    const int bm = blockIdx.x & 127;
    const int bn = blockIdx.x >> 7;

    const int r32 = tid >> 3;
    const int cb  = tid & 7;
    const int cg  = cb ^ (r32 & 7);
    const u16* gA0 = A  + (size_t)(bm * 64 + r32) * K + cg * 8;
    const u16* gA1 = A  + (size_t)(bm * 64 + 32 + r32) * K + cg * 8;
    const u16* gB0 = BT + (size_t)(bn * 64 + r32) * K + cg * 8;
    const u16* gB1 = BT + (size_t)(bn * 64 + 32 + r32) * K + cg * 8;
    u16* lAp0 = lA + tid * 8;
    u16* lAp1 = lA + 2048 + tid * 8;
    u16* lBp0 = lB + tid * 8;
    u16* lBp1 = lB + 2048 + tid * 8;

    floatx4 acc[2][2] = {};

    for (int k0 = 0; k0 < K; k0 += 64) {
        __builtin_amdgcn_global_load_lds(
            (const __attribute__((address_space(1))) u32*)(const void*)(gA0 + k0),
            (__attribute__((address_space(3))) u32*)(void*)lAp0, 16, 0, 0);
        __builtin_amdgcn_global_load_lds(
            (const __attribute__((address_space(1))) u32*)(const void*)(gA1 + k0),
            (__attribute__((address_space(3))) u32*)(void*)lAp1, 16, 0, 0);
        __builtin_amdgcn_global_load_lds(
            (const __attribute__((address_space(1))) u32*)(const void*)(gB0 + k0),
            (__attribute__((address_space(3))) u32*)(void*)lBp0, 16, 0, 0);
        __builtin_amdgcn_global_load_lds(
            (const __attribute__((address_space(1))) u32*)(const void*)(gB1 + k0),
            (__attribute__((address_space(3))) u32*)(void*)lBp1, 16, 0, 0);
        __syncthreads();   // barrier semantics drain vmcnt first

        short8 af[2][2], bfr[2][2];
#pragma unroll
        for (int im = 0; im < 2; ++im) {
            int row = wm + im * 16 + m16;
#pragma unroll
            for (int kk = 0; kk < 2; ++kk) {
                int slot = (kk * 4 + q) ^ (m16 & 7);
                af[im][kk] = *(const short8*)&lA[row * 64 + slot * 8];
            }
        }
#pragma unroll
        for (int in = 0; in < 2; ++in) {
            int row = wn + in * 16 + m16;
#pragma unroll
            for (int kk = 0; kk < 2; ++kk) {
                int slot = (kk * 4 + q) ^ (m16 & 7);
                bfr[in][kk] = *(const short8*)&lB[row * 64 + slot * 8];
            }
        }
#pragma unroll
        for (int kk = 0; kk < 2; ++kk)
#pragma unroll
            for (int im = 0; im < 2; ++im)
#pragma unroll
                for (int in = 0; in < 2; ++in)
                    acc[im][in] = __builtin_amdgcn_mfma_f32_16x16x32_bf16(
                        af[im][kk], bfr[in][kk], acc[im][in], 0, 0, 0);
        __syncthreads();
    }

    // epilogue: C/D layout col = lane&15, row = q*4 + reg  [measured m89/m91]
#pragma unroll
    for (int im = 0; im < 2; ++im) {
#pragma unroll
        for (int in = 0; in < 2; ++in) {
            int col = bn * 64 + wn + in * 16 + m16;
            float bvf = bias[col];
#pragma unroll
            for (int r = 0; r < 4; ++r) {
                int row = bm * 64 + wm + im * 16 + q * 4 + r;
                float v = softplusf(acc[im][in][r] + bvf);
                if (outf) outf[(size_t)row * 512 + col] = v;
                else      outb[(size_t)row * 512 + col] = f2bf(v * snorm[row]);
            }
        }
    }
}

// ---------------- PERSISTENT MEGA-KERNEL: all 9 phases, 8 grid barriers ----------------
__global__ __launch_bounds__(256, 8) void fused_gnn(
    const float* __restrict__ adj,
    const float* __restrict__ emb, const float* __restrict__ pos,
    const float* __restrict__ W0f, const float* __restrict__ W1f,
    const float* __restrict__ W2f, const float* __restrict__ W3f,
    const float* __restrict__ b0, const float* __restrict__ b1,
    const float* __restrict__ b2, const float* __restrict__ b3,
    u16* __restrict__ T0, u16* __restrict__ T1,
    u16* __restrict__ T2, u16* __restrict__ T3,
    int* __restrict__ deg, float* __restrict__ snorm,
    u32* __restrict__ edges, u16* __restrict__ buf0, u16* __restrict__ buf1,
    float* __restrict__ out, u64* bar)
{
    // LDS UNION (phases are barrier-separated): gemm lA+lB 16K | spmm 2K | p0 4.2K
    // 16.4KB/block -> 8 blocks/CU fit (LDS limit 9, launch_bounds limit 8)
    __shared__ __align__(16) char smem[16384];
    u16* lA    = (u16*)smem;
    u16* lB    = (u16*)(smem + 8192);
    int* sh    = (int*)smem;
    char* p0raw = smem;

    const int tid = threadIdx.x;
    const int wave = tid >> 6, lane = tid & 63;

    // ---- Phase 0: build graph + concat (vb<2048) | weight transpose (vb>=2048) ----
    for (int vb = blockIdx.x; vb < 3072; vb += NB) {
        __syncthreads();                 // protect smem reuse across iterations
        if (vb < 2048) {
            int* cnt = (int*)p0raw;
            const int i = vb * 4 + wave;
            if (tid < 4) cnt[tid] = 0;
            __syncthreads();
            const uint4* rowp = (const uint4*)(adj + (size_t)i * NN);
            u32* erow = edges + (size_t)i * CAP;
#pragma unroll 4
            for (int it = 0; it < 32; ++it) {            // 32 * 64 lanes * 4 f32 = 8192
                uint4 v = rowp[it * 64 + lane];
                int jb = (it * 64 + lane) * 4;
                u32 w[4] = { v.x, v.y, v.z, v.w };
#pragma unroll
                for (int e = 0; e < 4; ++e) {
                    int j = jb + e;
                    if ((i != j) && ((w[e] & 0x7FFFFFFFu) != 0)) {
                        int slot = atomicAdd(&cnt[wave], 1);   // LDS atomic, wave-local
                        if (slot < CAP) erow[slot] = (u32)j;
                    }
                }
            }
            __syncthreads();
            int c = cnt[wave];
            float s = rsqrtf((float)max(c, 1));
            if (lane == 0) { deg[i] = c; snorm[i] = s; }
#pragma unroll
            for (int h = 0; h < 2; ++h) {
                int f = lane + h * 64;
                float v = (f < 125) ? emb[(size_t)i * 125 + f] : pos[(size_t)i * 3 + (f - 125)];
                buf0[(size_t)i * 128 + f] = f2bf(v * s);
            }
        } else {
            float (*tile)[33] = (float(*)[33])p0raw;
            int b2 = vb - 2048;
            int z = b2 >> 8, rem = b2 & 255;
            const float* W = (z == 0) ? W0f : (z == 1) ? W1f : (z == 2) ? W2f : W3f;
            u16* WT       = (z == 0) ? T0 : (z == 1) ? T1 : (z == 2) ? T2 : T3;
            const int K = (z == 0) ? 128 : 512;
            int bx = (rem & 15) * 32;   // n
            int by = (rem >> 4) * 32;   // k
            int tx = tid & 31, ty = tid >> 5;
            if (by < K) {
#pragma unroll
                for (int yy = ty; yy < 32; yy += 8)
                    tile[yy][tx] = W[(size_t)(by + yy) * 512 + bx + tx];
            }
            __syncthreads();
            if (by < K) {
#pragma unroll
                for (int yy = ty; yy < 32; yy += 8)
                    WT[(size_t)(bx + yy) * K + by + tx] = f2bf(tile[tx][yy]);
            }
        }
    }

    gridbar(bar);

    // ---- Layer 0: spmm F=128, GEMM K=128 ----
    spmm128_phase(sh, edges, deg, snorm, (const u32*)buf0, (u32*)buf1);
    gridbar(bar);
    if (blockIdx.x < 1024)
        gemm_phase(lA, lB, buf1, T0, b0, snorm, nullptr, buf0, 128);

    // ---- Layers 1..3: spmm F=512, GEMM K=512 ----
    const u16* Wt[4] = { T0, T1, T2, T3 };
    const float* bv[4] = { b0, b1, b2, b3 };
    for (int l = 1; l < 4; ++l) {
        gridbar(bar);
        spmm512_phase(sh, edges, deg, snorm, (const uint4*)buf0, (uint4*)buf1);
        gridbar(bar);
        if (blockIdx.x < 1024)
            gemm_phase(lA, lB, buf1, Wt[l], bv[l], snorm,
                       (l == 3) ? out : nullptr, (l == 3) ? nullptr : buf0, 512);
    }
}

extern "C" void kernel_launch(void* const* d_in, const int* in_sizes, int n_in,
                              void* d_out, int out_size, void* d_ws, size_t ws_size,
                              hipStream_t stream)
{
    const float* atom_pos = (const float*)d_in[0];
    const float* dist_adj = (const float*)d_in[1];
    const float* atom_emb = (const float*)d_in[2];
    const float* Wm[4] = { (const float*)d_in[3], (const float*)d_in[5],
                           (const float*)d_in[7], (const float*)d_in[9] };
    const float* bv[4] = { (const float*)d_in[4], (const float*)d_in[6],
                           (const float*)d_in[8], (const float*)d_in[10] };

    char* p = (char*)d_ws;
    auto alloc = [&](size_t n) { char* r = p; p += (n + 255) & ~(size_t)255; return r; };
    u64*   bar   = (u64*)alloc(256);
    int*   deg   = (int*)alloc(NN * 4);
    float* snorm = (float*)alloc(NN * 4);
    u32*   edges = (u32*)alloc((size_t)NN * CAP * 4);
    u16*   wt[4];
    wt[0] = (u16*)alloc(512 * 128 * 2);
    wt[1] = (u16*)alloc(512 * 512 * 2);
    wt[2] = (u16*)alloc(512 * 512 * 2);
    wt[3] = (u16*)alloc(512 * 512 * 2);
    u16* buf0 = (u16*)alloc((size_t)NN * 512 * 2);
    u16* buf1 = (u16*)alloc((size_t)NN * 512 * 2);

    // barrier counter must start at 0 (ws may be poisoned between iterations)
    hipMemsetAsync(bar, 0, sizeof(u64), stream);

    fused_gnn<<<NB, 256, 0, stream>>>(
        dist_adj, atom_emb, atom_pos,
        Wm[0], Wm[1], Wm[2], Wm[3],
        bv[0], bv[1], bv[2], bv[3],
        wt[0], wt[1], wt[2], wt[3],
        deg, snorm, edges, buf0, buf1, (float*)d_out, bar);
}

// Round 3
// 554.991 us; speedup vs baseline: 4.4915x; 4.4915x over previous
//
#include <hip/hip_runtime.h>

typedef unsigned short u16;
typedef unsigned int u32;

#define NN 8192
#define CAP 128

typedef __attribute__((ext_vector_type(8))) short short8;
typedef __attribute__((ext_vector_type(4))) float floatx4;

__device__ __forceinline__ u16 f2bf(float f) {
    union { float f; u32 i; } w;
    w.f = f;
    u32 i = w.i;
    u32 r = (i + 0x7FFFu + ((i >> 16) & 1u)) >> 16;
    return (u16)r;
}
__device__ __forceinline__ float lo_bf(u32 v) {
    union { u32 i; float f; } w;
    w.i = v << 16;
    return w.f;
}
__device__ __forceinline__ float hi_bf(u32 v) {
    union { u32 i; float f; } w;
    w.i = v & 0xFFFF0000u;
    return w.f;
}
__device__ __forceinline__ float softplusf(float x) {
    return fmaxf(x, 0.0f) + log1pf(expf(-fabsf(x)));
}

// ---------------- PROLOGUE MEGA-KERNEL ----------------
// Blocks 0..2047:   build_graph (wave-per-row edge list + degree + rsqrt norm)
//                   then concat+scale the same 4 rows' features (no cross-block dep).
// Blocks 2048..3071: 32x32 weight transposes f32->bf16 (independent; ride along
//                   ~free under the HBM-bound adjacency stream).
__global__ __launch_bounds__(256) void prologue(
    const float* __restrict__ adj,
    const float* __restrict__ emb, const float* __restrict__ pos,
    const float* __restrict__ W0, const float* __restrict__ W1,
    const float* __restrict__ W2, const float* __restrict__ W3,
    u16* __restrict__ T0, u16* __restrict__ T1,
    u16* __restrict__ T2, u16* __restrict__ T3,
    int* __restrict__ deg, float* __restrict__ snorm,
    u32* __restrict__ edges, u16* __restrict__ feat0)
{
    __shared__ char shraw[32 * 33 * 4];   // union: cnt[4] (build) | tile[32][33] (transpose)
    const int b = blockIdx.x;

    if (b < 2048) {
        // ---- build_graph + fused concat ----
        int* cnt = (int*)shraw;
        const int wave = threadIdx.x >> 6, lane = threadIdx.x & 63;
        const int i = b * 4 + wave;
        if (threadIdx.x < 4) cnt[threadIdx.x] = 0;
        __syncthreads();
        const uint4* rowp = (const uint4*)(adj + (size_t)i * NN);
        u32* erow = edges + (size_t)i * CAP;
#pragma unroll 4
        for (int it = 0; it < 32; ++it) {            // 32 * 64 lanes * 4 f32 = 8192
            uint4 v = rowp[it * 64 + lane];
            int jb = (it * 64 + lane) * 4;
            u32 w[4] = { v.x, v.y, v.z, v.w };
#pragma unroll
            for (int e = 0; e < 4; ++e) {
                int j = jb + e;
                if ((i != j) && ((w[e] & 0x7FFFFFFFu) != 0)) {
                    int slot = atomicAdd(&cnt[wave], 1);   // LDS atomic, wave-local
                    if (slot < CAP) erow[slot] = (u32)j;
                }
            }
        }
        __syncthreads();
        int c = cnt[wave];
        float s = rsqrtf((float)max(c, 1));
        if (lane == 0) { deg[i] = c; snorm[i] = s; }
        // concat [emb|pos] row i, pre-scaled by s -> bf16 (2 cols per lane)
#pragma unroll
        for (int h = 0; h < 2; ++h) {
            int f = lane + h * 64;
            float v = (f < 125) ? emb[(size_t)i * 125 + f] : pos[(size_t)i * 3 + (f - 125)];
            feat0[(size_t)i * 128 + f] = f2bf(v * s);
        }
    } else {
        // ---- weight transposes ----
        float (*tile)[33] = (float(*)[33])shraw;
        int b2 = b - 2048;
        int z = b2 >> 8, rem = b2 & 255;
        const float* W = (z == 0) ? W0 : (z == 1) ? W1 : (z == 2) ? W2 : W3;
        u16* WT       = (z == 0) ? T0 : (z == 1) ? T1 : (z == 2) ? T2 : T3;
        const int K = (z == 0) ? 128 : 512;
        const int N = 512;
        int bx = (rem & 15) * 32;   // n
        int by = (rem >> 4) * 32;   // k
        if (by >= K) return;        // block-uniform
        int tx = threadIdx.x & 31, ty = threadIdx.x >> 5;
#pragma unroll
        for (int yy = ty; yy < 32; yy += 8)
            tile[yy][tx] = W[(size_t)(by + yy) * N + bx + tx];
        __syncthreads();
#pragma unroll
        for (int yy = ty; yy < 32; yy += 8)
            WT[(size_t)(bx + yy) * K + by + tx] = f2bf(tile[tx][yy]);
    }
}

// ---------------- SpMM F=512: out[j,:] = snorm[j] * sum_{i in N(j)} featS[i,:] ----------------
// featS PRE-SCALED by snorm[src]; single-pass uint4 (full 1KB row per wave-load).
__global__ __launch_bounds__(256) void spmm512(
    const u32* __restrict__ edges, const int* __restrict__ deg,
    const float* __restrict__ snorm,
    const uint4* __restrict__ feat4, uint4* __restrict__ out4)
{
    __shared__ int sh_i[4][CAP];
    const int wave = threadIdx.x >> 6, lane = threadIdx.x & 63;
    const int j = blockIdx.x * 4 + wave;
    const int cnt = min(deg[j], CAP);
    for (int c = lane; c < cnt; c += 64)
        sh_i[wave][c] = (int)edges[(size_t)j * CAP + c];
    __syncthreads();
    float a[8] = {};
#pragma unroll 4
    for (int c = 0; c < cnt; ++c) {
        uint4 v = feat4[(size_t)sh_i[wave][c] * 64 + lane];   // 512 cols = 64 uint4
        a[0] += lo_bf(v.x); a[1] += hi_bf(v.x);
        a[2] += lo_bf(v.y); a[3] += hi_bf(v.y);
        a[4] += lo_bf(v.z); a[5] += hi_bf(v.z);
        a[6] += lo_bf(v.w); a[7] += hi_bf(v.w);
    }
    float sj = snorm[j];
    uint4 o;
    o.x = (u32)f2bf(a[0] * sj) | ((u32)f2bf(a[1] * sj) << 16);
    o.y = (u32)f2bf(a[2] * sj) | ((u32)f2bf(a[3] * sj) << 16);
    o.z = (u32)f2bf(a[4] * sj) | ((u32)f2bf(a[5] * sj) << 16);
    o.w = (u32)f2bf(a[6] * sj) | ((u32)f2bf(a[7] * sj) << 16);
    out4[(size_t)j * 64 + lane] = o;
}

// ---------------- SpMM F=128 (layer 0): u32 loads, all 64 lanes active ----------------
__global__ __launch_bounds__(256) void spmm128(
    const u32* __restrict__ edges, const int* __restrict__ deg,
    const float* __restrict__ snorm,
    const u32* __restrict__ feat1, u32* __restrict__ out1)
{
    __shared__ int sh_i[4][CAP];
    const int wave = threadIdx.x >> 6, lane = threadIdx.x & 63;
    const int j = blockIdx.x * 4 + wave;
    const int cnt = min(deg[j], CAP);
    for (int c = lane; c < cnt; c += 64)
        sh_i[wave][c] = (int)edges[(size_t)j * CAP + c];
    __syncthreads();
    float a0 = 0.f, a1 = 0.f;
#pragma unroll 4
    for (int c = 0; c < cnt; ++c) {
        u32 v = feat1[(size_t)sh_i[wave][c] * 64 + lane];   // 128 cols = 64 u32
        a0 += lo_bf(v); a1 += hi_bf(v);
    }
    float sj = snorm[j];
    out1[(size_t)j * 64 + lane] = (u32)f2bf(a0 * sj) | ((u32)f2bf(a1 * sj) << 16);
}

// ---------------- GEMM: out = softplus(A[M,K] @ W + b) [* snorm[row] inner layers] ----------------
// R13: B-tile reuse — each block computes TWO adjacent 64-row M-tiles sharing one
// 64-col B-tile. Staged bytes/output -25%, MFMA-per-barrier-pair 2x. Grid (64,8)
// = 512 blocks = 2/CU; __launch_bounds__(256,2) -> VGPR cap 256 (no spill; R2
// lesson: (256,8) forced 32 VGPR + 204MB scratch). Swizzle + fragment code
// byte-identical per tile to the verified R0 kernel.
__global__ __launch_bounds__(256, 2) void gemm_bias_softplus(
    const u16* __restrict__ A, const u16* __restrict__ BT,
    const float* __restrict__ bias, const float* __restrict__ snorm,
    float* __restrict__ outf, u16* __restrict__ outb,
    int M, int N, int K)
{
    __shared__ u16 lA[2][64 * 64];   // two A tiles, 8KB each, swizzled slots
    __shared__ u16 lB[64 * 64];      // [col][k] 8KB, swizzled slots
    const int tid = threadIdx.x;
    const int wave = tid >> 6;
    const int lane = tid & 63;
    const int q = lane >> 4;
    const int m16 = lane & 15;
    const int wm = (wave >> 1) * 32;
    const int wn = (wave & 1) * 32;
    const int t0 = blockIdx.x * 2;       // M-tiles t0, t0+1
    const int bn = blockIdx.y;

    const int r32 = tid >> 3;             // 0..31 staging row within half
    const int cb  = tid & 7;              // LDS slot index 0..7
    const int cg  = cb ^ (r32 & 7);       // swizzled global col block
    const u16* gA00 = A  + (size_t)(t0 * 64 + r32) * K + cg * 8;
    const u16* gA01 = A  + (size_t)(t0 * 64 + 32 + r32) * K + cg * 8;
    const u16* gA10 = A  + (size_t)((t0 + 1) * 64 + r32) * K + cg * 8;
    const u16* gA11 = A  + (size_t)((t0 + 1) * 64 + 32 + r32) * K + cg * 8;
    const u16* gB0  = BT + (size_t)(bn * 64 + r32) * K + cg * 8;
    const u16* gB1  = BT + (size_t)(bn * 64 + 32 + r32) * K + cg * 8;
    u16* lA00 = &lA[0][0] + tid * 8;
    u16* lA01 = &lA[0][0] + 2048 + tid * 8;
    u16* lA10 = &lA[1][0] + tid * 8;
    u16* lA11 = &lA[1][0] + 2048 + tid * 8;
    u16* lBp0 = lB + tid * 8;
    u16* lBp1 = lB + 2048 + tid * 8;

    floatx4 acc[2][2][2] = {};   // [tile][im][in]

    for (int k0 = 0; k0 < K; k0 += 64) {
        __builtin_amdgcn_global_load_lds(
            (const __attribute__((address_space(1))) u32*)(const void*)(gA00 + k0),
            (__attribute__((address_space(3))) u32*)(void*)lA00, 16, 0, 0);
        __builtin_amdgcn_global_load_lds(
            (const __attribute__((address_space(1))) u32*)(const void*)(gA01 + k0),
            (__attribute__((address_space(3))) u32*)(void*)lA01, 16, 0, 0);
        __builtin_amdgcn_global_load_lds(
            (const __attribute__((address_space(1))) u32*)(const void*)(gA10 + k0),
            (__attribute__((address_space(3))) u32*)(void*)lA10, 16, 0, 0);
        __builtin_amdgcn_global_load_lds(
            (const __attribute__((address_space(1))) u32*)(const void*)(gA11 + k0),
            (__attribute__((address_space(3))) u32*)(void*)lA11, 16, 0, 0);
        __builtin_amdgcn_global_load_lds(
            (const __attribute__((address_space(1))) u32*)(const void*)(gB0 + k0),
            (__attribute__((address_space(3))) u32*)(void*)lBp0, 16, 0, 0);
        __builtin_amdgcn_global_load_lds(
            (const __attribute__((address_space(1))) u32*)(const void*)(gB1 + k0),
            (__attribute__((address_space(3))) u32*)(void*)lBp1, 16, 0, 0);
        __syncthreads();   // barrier semantics drain vmcnt first

        short8 bfr[2][2];
#pragma unroll
        for (int in = 0; in < 2; ++in) {
            int row = wn + in * 16 + m16;
#pragma unroll
            for (int kk = 0; kk < 2; ++kk) {
                int slot = (kk * 4 + q) ^ (m16 & 7);
                bfr[in][kk] = *(const short8*)&lB[row * 64 + slot * 8];
            }
        }
#pragma unroll
        for (int t = 0; t < 2; ++t) {
            short8 af[2][2];
#pragma unroll
            for (int im = 0; im < 2; ++im) {
                int row = wm + im * 16 + m16;
#pragma unroll
                for (int kk = 0; kk < 2; ++kk) {
                    int slot = (kk * 4 + q) ^ (m16 & 7);
                    af[im][kk] = *(const short8*)&lA[t][row * 64 + slot * 8];
                }
            }
#pragma unroll
            for (int kk = 0; kk < 2; ++kk)
#pragma unroll
                for (int im = 0; im < 2; ++im)
#pragma unroll
                    for (int in = 0; in < 2; ++in)
                        acc[t][im][in] = __builtin_amdgcn_mfma_f32_16x16x32_bf16(
                            af[im][kk], bfr[in][kk], acc[t][im][in], 0, 0, 0);
        }
        __syncthreads();
    }

    // epilogue: C/D layout col = lane&15, row = q*4 + reg  [measured m89/m91]
#pragma unroll
    for (int t = 0; t < 2; ++t) {
#pragma unroll
        for (int im = 0; im < 2; ++im) {
#pragma unroll
            for (int in = 0; in < 2; ++in) {
                int col = bn * 64 + wn + in * 16 + m16;
                float bvf = bias[col];
#pragma unroll
                for (int r = 0; r < 4; ++r) {
                    int row = (t0 + t) * 64 + wm + im * 16 + q * 4 + r;
                    float v = softplusf(acc[t][im][in][r] + bvf);
                    if (outf) outf[(size_t)row * N + col] = v;
                    else      outb[(size_t)row * N + col] = f2bf(v * snorm[row]);
                }
            }
        }
    }
}

extern "C" void kernel_launch(void* const* d_in, const int* in_sizes, int n_in,
                              void* d_out, int out_size, void* d_ws, size_t ws_size,
                              hipStream_t stream)
{
    const float* atom_pos = (const float*)d_in[0];
    const float* dist_adj = (const float*)d_in[1];
    const float* atom_emb = (const float*)d_in[2];
    const float* Wm[4] = { (const float*)d_in[3], (const float*)d_in[5],
                           (const float*)d_in[7], (const float*)d_in[9] };
    const float* bv[4] = { (const float*)d_in[4], (const float*)d_in[6],
                           (const float*)d_in[8], (const float*)d_in[10] };

    char* p = (char*)d_ws;
    auto alloc = [&](size_t n) { char* r = p; p += (n + 255) & ~(size_t)255; return r; };
    int*   deg   = (int*)alloc(NN * 4);
    float* snorm = (float*)alloc(NN * 4);
    u32*   edges = (u32*)alloc((size_t)NN * CAP * 4);
    u16*   wt[4];
    wt[0] = (u16*)alloc(512 * 128 * 2);
    wt[1] = (u16*)alloc(512 * 512 * 2);
    wt[2] = (u16*)alloc(512 * 512 * 2);
    wt[3] = (u16*)alloc(512 * 512 * 2);
    u16* buf0 = (u16*)alloc((size_t)NN * 512 * 2);
    u16* buf1 = (u16*)alloc((size_t)NN * 512 * 2);

    prologue<<<2048 + 1024, 256, 0, stream>>>(
        dist_adj, atom_emb, atom_pos,
        Wm[0], Wm[1], Wm[2], Wm[3], wt[0], wt[1], wt[2], wt[3],
        deg, snorm, edges, buf0);

    const u16* feat = buf0;
    int F = 128;
    for (int l = 0; l < 4; ++l) {
        if (F == 128)
            spmm128<<<NN / 4, 256, 0, stream>>>(edges, deg, snorm,
                                                (const u32*)feat, (u32*)buf1);
        else
            spmm512<<<NN / 4, 256, 0, stream>>>(edges, deg, snorm,
                                                (const uint4*)feat, (uint4*)buf1);
        float* outf = (l == 3) ? (float*)d_out : nullptr;
        u16*   outb = (l == 3) ? nullptr : buf0;
        gemm_bias_softplus<<<dim3(NN / 128, 512 / 64), 256, 0, stream>>>(
            buf1, wt[l], bv[l], snorm, outf, outb, NN, 512, F);
        feat = buf0;
        F = 512;
    }
}